// Round 7
// baseline (51.420 us; speedup 1.0000x reference)
//
#include <hip/hip_runtime.h>

#define GAMMA_F 1.1f
#define F_DIM 5
#define NB 256    // x-bins
#define NT 256    // point tiles
#define XMIN_F -75.2f
#define XRANGE_F 150.4f
#define CAP 2048  // max hits collected per box (data max ~610)

__device__ __forceinline__ int prefix_lt(unsigned long long m) {
  return __builtin_amdgcn_mbcnt_hi(
      (unsigned)(m >> 32), __builtin_amdgcn_mbcnt_lo((unsigned)m, 0u));
}

// Bin is clamped -> correctness never depends on the hardcoded range
// (out-of-range data just lands in edge bins; only perf would suffer).
__device__ __forceinline__ int xbin(float x) {
  const int b = (int)((x - XMIN_F) * ((float)NB / XRANGE_F));
  return min(NB - 1, max(0, b));
}

// Exact radius threshold (proven R2): largest f32 s with sqrt_rn(s) <= r.
__device__ __forceinline__ float smax_of(float dx_size, float dy_size) {
  const float hdx = __fmul_rn(dx_size, 0.5f);
  const float hdy = __fmul_rn(dy_size, 0.5f);
  const float r = __fmul_rn(
      __fsqrt_rn(__fadd_rn(__fmul_rn(hdx, hdx), __fmul_rn(hdy, hdy))),
      GAMMA_F);
  const unsigned ru = __float_as_uint(r);
  const float rsucc = __uint_as_float(ru + 1u);        // r > 0, finite
  const double m = ((double)r + (double)rsucc) * 0.5;  // exact
  const double m2 = m * m;                             // exact
  const bool incl = ((ru & 1u) == 0u);  // RN tie-to-even lands on r
  const float c1 = (float)m2;
  const double c1d = (double)c1;
  const bool keep = incl ? (c1d <= m2) : (c1d < m2);
  return keep ? c1 : __uint_as_float(__float_as_uint(c1) - 1u);
}

// ---- K1: per-tile x-histogram -> hist2dT[bin][tile] -------------------------
__global__ void __launch_bounds__(256) hist_kernel(
    const float* __restrict__ pts, int* __restrict__ hist2dT, int N,
    int TILE) {
  __shared__ int h[NB];
  const int t = blockIdx.x;
  for (int i = threadIdx.x; i < NB; i += 256) h[i] = 0;
  __syncthreads();
  const int s = t * TILE, e = min(s + TILE, N);
  for (int i = s + (int)threadIdx.x; i < e; i += 256)
    atomicAdd(&h[xbin(pts[(size_t)i * F_DIM])], 1);
  __syncthreads();
  for (int b = threadIdx.x; b < NB; b += 256) hist2dT[b * NT + t] = h[b];
}

// ---- K2: per-bin exclusive scan over tiles + bin totals ---------------------
__global__ void __launch_bounds__(64) binscan_kernel(
    const int* __restrict__ hist2dT, int* __restrict__ colpfx,
    int* __restrict__ tot) {
  const int b = blockIdx.x;
  const int lane = threadIdx.x;
  const int4 v = ((const int4*)(hist2dT + b * NT))[lane];
  const int s0 = v.x;
  const int s1 = s0 + v.y;
  const int s2 = s1 + v.z;
  const int s3 = s2 + v.w;  // inclusive within quad
  int sv = s3;
#pragma unroll
  for (int d = 1; d < 64; d <<= 1) {
    const int tmp = __shfl_up(sv, d, 64);
    if (lane >= d) sv += tmp;
  }
  const int excl = sv - s3;
  int4 o;
  o.x = excl;
  o.y = excl + s0;
  o.z = excl + s1;
  o.w = excl + s2;
  ((int4*)(colpfx + b * NT))[lane] = o;
  if (lane == 63) tot[b] = sv;
}

// ---- K3: scatter (x,y,idx) into bin-major order -----------------------------
__global__ void __launch_bounds__(256) scatter_kernel(
    const float* __restrict__ pts, const int* __restrict__ colpfx,
    const int* __restrict__ tot, float2* __restrict__ sxy,
    int* __restrict__ sidx, int N, int TILE) {
  __shared__ int binStart[NB];
  __shared__ int lcnt[NB];
  __shared__ int wtot[4], woff[4];
  const int t = blockIdx.x;
  const int tid = threadIdx.x;
  const int lane = tid & 63;
  const int wid = tid >> 6;

  const int v = tot[tid];  // NB == blockDim == 256
  int sv = v;
#pragma unroll
  for (int d = 1; d < 64; d <<= 1) {
    const int tmp = __shfl_up(sv, d, 64);
    if (lane >= d) sv += tmp;
  }
  if (lane == 63) wtot[wid] = sv;
  __syncthreads();
  if (tid == 0) {
    int a = 0;
#pragma unroll
    for (int w = 0; w < 4; ++w) {
      woff[w] = a;
      a += wtot[w];
    }
  }
  __syncthreads();
  binStart[tid] = sv - v + woff[wid];  // exclusive prefix
  lcnt[tid] = 0;
  __syncthreads();

  const int s = t * TILE, e = min(s + TILE, N);
  for (int i = s + tid; i < e; i += 256) {
    const float x = pts[(size_t)i * F_DIM];
    const float y = pts[(size_t)i * F_DIM + 1];
    const int b = xbin(x);
    const int off = atomicAdd(&lcnt[b], 1);  // order arbitrary; sorted later
    const int pos = binStart[b] + colpfx[b * NT + t] + off;
    sxy[pos] = make_float2(x, y);
    sidx[pos] = i;
  }
}

// ---- K4: per box: test candidates, collect hit indices, sort, gather -------
template <int BLK>
__global__ void __launch_bounds__(BLK) box_kernel(
    const float* __restrict__ pts, const float* __restrict__ boxes,
    const int* __restrict__ tot, const float2* __restrict__ sxy,
    const int* __restrict__ sidx, float* __restrict__ out, int N, int S) {
  constexpr int NWAVES = BLK / 64;
  __shared__ int binStart[NB + 1];
  __shared__ int hit[CAP];
  __shared__ int nhit;
  __shared__ int wtot[NWAVES], woff[NWAVES];

  const int bx = blockIdx.x;
  const int tid = threadIdx.x;
  const int lane = tid & 63;
  const int wid = tid >> 6;

  // Block-local scan of bin totals -> binStart[0..NB].
  if (tid < NB) {
    const int v = tot[tid];
    int sv = v;
#pragma unroll
    for (int d = 1; d < 64; d <<= 1) {
      const int tmp = __shfl_up(sv, d, 64);
      if (lane >= d) sv += tmp;
    }
    if (lane == 63) wtot[wid] = sv;
    binStart[tid + 1] = sv;  // within-wave inclusive, fixed up below
  }
  if (tid == 0) {
    nhit = 0;
    binStart[0] = 0;
  }
  __syncthreads();
  if (tid == 0) {
    int a = 0;
#pragma unroll
    for (int w = 0; w < NB / 64; ++w) {
      woff[w] = a;
      a += wtot[w];
    }
  }
  __syncthreads();
  if (tid < NB) binStart[tid + 1] += woff[wid];
  __syncthreads();

  // Box params (uniform).
  const float* bp = boxes + bx * 7;
  const float cx = bp[0], cy = bp[1];
  const float smax = smax_of(bp[3], bp[4]);
  const float hdx = __fmul_rn(bp[3], 0.5f);
  const float hdy = __fmul_rn(bp[4], 0.5f);
  const float r = __fmul_rn(
      __fsqrt_rn(__fadd_rn(__fmul_rn(hdx, hdx), __fmul_rn(hdy, hdy))),
      GAMMA_F);
  // +/-1 bin slack (0.587 m) dwarfs any f32 rounding at the circle boundary.
  const int lob = max(0, xbin(__fsub_rn(cx, r)) - 1);
  const int hib = min(NB - 1, xbin(__fadd_rn(cx, r)) + 1);
  const int cs = binStart[lob];
  const int ce = binStart[hib + 1];

  // Test candidates; collect hit original-indices (order arbitrary).
  for (int j = cs + tid; j < ce; j += BLK) {
    const float2 p = sxy[j];
    const float dx = __fsub_rn(p.x, cx);
    const float dy = __fsub_rn(p.y, cy);
    const float s = __fadd_rn(__fmul_rn(dx, dx), __fmul_rn(dy, dy));
    const bool sel = (s <= smax);
    const unsigned long long m = __ballot(sel);
    if (m) {
      int base = 0;
      if (lane == 0) base = atomicAdd(&nhit, __popcll(m));
      base = __shfl(base, 0, 64);  // lane0 active whenever any lane is
      const int pos = base + prefix_lt(m);
      if (sel && pos < CAP) hit[pos] = sidx[j];
    }
  }
  __syncthreads();

  const int K = min(nhit, CAP);  // data max ~610 << CAP
  int Kp2 = 1;
  while (Kp2 < K) Kp2 <<= 1;
  for (int i = K + tid; i < Kp2; i += BLK) hit[i] = 0x7FFFFFFF;
  __syncthreads();

  // Bitonic sort ascending over Kp2 elements.
  for (int k = 2; k <= Kp2; k <<= 1) {
    for (int j2 = k >> 1; j2 > 0; j2 >>= 1) {
      for (int i = tid; i < Kp2; i += BLK) {
        const int p = i ^ j2;
        if (p > i) {
          const int a = hit[i];
          const int b2 = hit[p];
          const bool asc = ((i & k) == 0);
          if ((a > b2) == asc) {
            hit[i] = b2;
            hit[p] = a;
          }
        }
      }
      __syncthreads();
    }
  }

  // First S sorted indices -> gather features; tail -> zeros.
  if (tid < S) {
    float* o = out + ((size_t)bx * S + tid) * F_DIM;
    if (tid < K) {
      const float* p = pts + (size_t)hit[tid] * F_DIM;
      o[0] = p[0];
      o[1] = p[1];
      o[2] = p[2];
      o[3] = p[3];
      o[4] = p[4];
    } else {
      o[0] = 0.0f;
      o[1] = 0.0f;
      o[2] = 0.0f;
      o[3] = 0.0f;
      o[4] = 0.0f;
    }
  }
}

// ---------------- Fallback: proven R1 single-kernel version ----------------
template <int BLOCK>
__global__ void __launch_bounds__(BLOCK) voxel_sampler_fallback(
    const float* __restrict__ pts, const float* __restrict__ boxes,
    float* __restrict__ out, int N, int S) {
  constexpr int NW = BLOCK / 64;
  const int b = blockIdx.x;
  const int tid = threadIdx.x;
  const int lane = tid & 63;
  const int wid = tid >> 6;

  const float cx = boxes[b * 7 + 0];
  const float cy = boxes[b * 7 + 1];
  const float hdx = __fmul_rn(boxes[b * 7 + 3], 0.5f);
  const float hdy = __fmul_rn(boxes[b * 7 + 4], 0.5f);
  const float r = __fmul_rn(
      __fsqrt_rn(__fadd_rn(__fmul_rn(hdx, hdx), __fmul_rn(hdy, hdy))),
      GAMMA_F);

  __shared__ int s_wsum[NW];
  __shared__ int s_count;
  if (tid == 0) s_count = 0;
  __syncthreads();

  float* outb = out + (size_t)b * S * F_DIM;

  for (int base = 0; base < N; base += BLOCK) {
    const int i = base + tid;
    bool sel = false;
    float x = 0.0f, y = 0.0f;
    if (i < N) {
      x = pts[i * F_DIM + 0];
      y = pts[i * F_DIM + 1];
      const float ddx = __fsub_rn(x, cx);
      const float ddy = __fsub_rn(y, cy);
      const float dis =
          __fsqrt_rn(__fadd_rn(__fmul_rn(ddx, ddx), __fmul_rn(ddy, ddy)));
      sel = (dis <= r);
    }
    const unsigned long long m = __ballot(sel);
    if (lane == 0) s_wsum[wid] = __popcll(m);
    __syncthreads();
    const int cbase = s_count;
    int wbase = 0;
    int tot = 0;
#pragma unroll
    for (int w = 0; w < NW; ++w) {
      const int v = s_wsum[w];
      if (w < wid) wbase += v;
      tot += v;
    }
    const int pos = cbase + wbase + __popcll(m & ((1ULL << lane) - 1ULL));
    if (sel && pos < S) {
      float* o = outb + pos * F_DIM;
      o[0] = x;
      o[1] = y;
      o[2] = pts[i * F_DIM + 2];
      o[3] = pts[i * F_DIM + 3];
      o[4] = pts[i * F_DIM + 4];
    }
    __syncthreads();
    if (tid == 0) s_count = cbase + tot;
    __syncthreads();
    if (cbase + tot >= S) break;
  }

  __syncthreads();
  int cnt = s_count;
  if (cnt > S) cnt = S;
  for (int j = cnt * F_DIM + tid; j < S * F_DIM; j += BLOCK) outb[j] = 0.0f;
}

extern "C" void kernel_launch(void* const* d_in, const int* in_sizes, int n_in,
                              void* d_out, int out_size, void* d_ws,
                              size_t ws_size, hipStream_t stream) {
  const float* pts = (const float*)d_in[0];
  const float* boxes = (const float*)d_in[1];
  float* out = (float*)d_out;

  const int N = in_sizes[0] / F_DIM;     // 200000
  const int B = in_sizes[1] / 7;         // 256
  const int S = out_size / (B * F_DIM);  // 128

  const int TILE = (N + NT - 1) / NT;

  const size_t sz_h = (size_t)NB * NT * sizeof(int);        // hist2dT
  const size_t off_c = (sz_h + 255) & ~(size_t)255;         // colpfx
  const size_t off_t = (off_c + sz_h + 255) & ~(size_t)255; // tot
  const size_t off_xy = (off_t + NB * sizeof(int) + 255) & ~(size_t)255;
  const size_t off_si =
      (off_xy + (size_t)N * sizeof(float2) + 255) & ~(size_t)255;
  const size_t need = off_si + (size_t)N * sizeof(int);

  constexpr int BLKD = 512;
  const bool fast = (ws_size >= need) && (S <= BLKD) && (S <= CAP) && (N > 0);

  if (fast) {
    char* ws = (char*)d_ws;
    int* hist2dT = (int*)ws;
    int* colpfx = (int*)(ws + off_c);
    int* tot = (int*)(ws + off_t);
    float2* sxy = (float2*)(ws + off_xy);
    int* sidx = (int*)(ws + off_si);

    hist_kernel<<<NT, 256, 0, stream>>>(pts, hist2dT, N, TILE);
    binscan_kernel<<<NB, 64, 0, stream>>>(hist2dT, colpfx, tot);
    scatter_kernel<<<NT, 256, 0, stream>>>(pts, colpfx, tot, sxy, sidx, N,
                                           TILE);
    box_kernel<BLKD><<<B, BLKD, 0, stream>>>(pts, boxes, tot, sxy, sidx, out,
                                             N, S);
  } else {
    voxel_sampler_fallback<1024><<<B, 1024, 0, stream>>>(pts, boxes, out, N,
                                                         S);
  }
}

// Round 8
// 24.352 us; speedup vs baseline: 2.1115x; 2.1115x over previous
//
#include <hip/hip_runtime.h>

#define GAMMA_F 1.1f
#define F_DIM 5
#define BOXG 8
#define MAX_NSEG 256
#define MAXL 1024  // max points per segment staged in LDS (8 KB)

__device__ __forceinline__ int prefix_lt(unsigned long long m) {
  return __builtin_amdgcn_mbcnt_hi(
      (unsigned)(m >> 32), __builtin_amdgcn_mbcnt_lo((unsigned)m, 0u));
}

// ---- Phase 1: block = 1 segment x 16 waves x 8 boxes each (128 boxes). ----
// Cold-cache regime (harness re-poisons 256MiB ws between replays -> L2/L3
// flushed): minimize redundant cold passes over pts (bpg=2) and maximize
// occupancy (launch_bounds caps VGPR at 64 -> 32 waves/CU).
// Box threshold smax: largest f32 s with sqrt_rn(s) <= r (exact, proven R2).
template <int NWAVE>
__global__ void __launch_bounds__(NWAVE * 64, 8) seg_lds_kernel(
    const float* __restrict__ pts, const float* __restrict__ boxes,
    int* __restrict__ cnt, unsigned short* __restrict__ idx, int N, int S,
    int NSEG, int L, int NGRP) {
  __shared__ __align__(16) float2 sxy[MAXL];

  const int tid = threadIdx.x;
  const int lane = tid & 63;
  const int wid = tid >> 6;
  const int bpg = NGRP / NWAVE;  // blocks per segment
  const int seg = blockIdx.x / bpg;
  const int bg = blockIdx.x - seg * bpg;
  const int grp = bg * NWAVE + wid;
  const int box0 = grp * BOXG;

  const int start = seg * L;
  const int end = min(start + L, N);
  const int npts = end - start;

  // Per-wave box params (registers).
  float cx[BOXG], cy[BOXG], smax[BOXG];
#pragma unroll
  for (int b = 0; b < BOXG; ++b) {
    const float* bx = boxes + (box0 + b) * 7;
    cx[b] = bx[0];
    cy[b] = bx[1];
    const float hdx = __fmul_rn(bx[3], 0.5f);
    const float hdy = __fmul_rn(bx[4], 0.5f);
    const float r = __fmul_rn(
        __fsqrt_rn(__fadd_rn(__fmul_rn(hdx, hdx), __fmul_rn(hdy, hdy))),
        GAMMA_F);
    const unsigned ru = __float_as_uint(r);
    const float rsucc = __uint_as_float(ru + 1u);        // r > 0, finite
    const double m = ((double)r + (double)rsucc) * 0.5;  // exact
    const double m2 = m * m;                             // exact
    const bool incl = ((ru & 1u) == 0u);  // RN tie-to-even lands on r
    const float c1 = (float)m2;
    const double c1d = (double)c1;
    const bool keep = incl ? (c1d <= m2) : (c1d < m2);
    smax[b] = keep ? c1 : __uint_as_float(__float_as_uint(c1) - 1u);
  }

  // Stage this segment's xy into LDS (once per block).
  for (int t = tid; t < npts; t += NWAVE * 64) {
    const float* p = pts + (size_t)(start + t) * F_DIM;
    sxy[t] = make_float2(p[0], p[1]);
  }
  __syncthreads();

  int c[BOXG];
#pragma unroll
  for (int b = 0; b < BOXG; ++b) c[b] = 0;

  const size_t ibase = ((size_t)box0 * NSEG + seg) * S;
  const float4* sxy4 = (const float4*)sxy;

#define PROCESS_8(RELBASE, X0, Y0, X1, Y1, G0, G1)                          \
  {                                                                         \
    const int rel = (RELBASE) + 2 * lane;                                   \
    _Pragma("unroll") for (int b = 0; b < BOXG; ++b) {                      \
      const float dx0 = __fsub_rn((X0), cx[b]);                             \
      const float dy0 = __fsub_rn((Y0), cy[b]);                             \
      const float s0 = __fadd_rn(__fmul_rn(dx0, dx0), __fmul_rn(dy0, dy0)); \
      const float dx1 = __fsub_rn((X1), cx[b]);                             \
      const float dy1 = __fsub_rn((Y1), cy[b]);                             \
      const float s1 = __fadd_rn(__fmul_rn(dx1, dx1), __fmul_rn(dy1, dy1)); \
      const bool sel0 = (G0) && (s0 <= smax[b]);                            \
      const bool sel1 = (G1) && (s1 <= smax[b]);                            \
      const unsigned long long m0 = __ballot(sel0);                         \
      const unsigned long long m1 = __ballot(sel1);                         \
      if (m0 | m1) {                                                        \
        const int p0 = prefix_lt(m0);                                       \
        const int p1 = prefix_lt(m1);                                       \
        const int r0 = c[b] + p0 + p1;                                      \
        const int r1 = c[b] + p0 + (sel0 ? 1 : 0) + p1;                     \
        unsigned short* mp = idx + ibase + (size_t)b * NSEG * S;            \
        if (sel0 && r0 < S) mp[r0] = (unsigned short)rel;                   \
        if (sel1 && r1 < S) mp[r1] = (unsigned short)(rel + 1);             \
        c[b] += __popcll(m0) + __popcll(m1);                                \
      }                                                                     \
    }                                                                       \
  }

  const int nfull = npts / 128;
  for (int it = 0; it < nfull; ++it) {
    const float4 q = sxy4[it * 64 + lane];  // ds_read_b128, 2 points
    PROCESS_8(it * 128, q.x, q.y, q.z, q.w, true, true);
  }
  const int relb = nfull * 128;
  if (relb < npts) {
    const float4 q = sxy4[nfull * 64 + lane];  // in-bounds (MAXL), masked
    const int rel = relb + 2 * lane;
    const bool g0 = (rel < npts);
    const bool g1 = (rel + 1 < npts);
    PROCESS_8(relb, q.x, q.y, q.z, q.w, g0, g1);
  }
#undef PROCESS_8

  if (lane == 0) {
#pragma unroll
    for (int b = 0; b < BOXG; ++b) cnt[(box0 + b) * NSEG + seg] = min(c[b], S);
  }
}

// ------- Phase 2: per box, prefix over segment counts + gather features ------
__global__ void __launch_bounds__(256) gather_kernel(
    const float* __restrict__ pts, const int* __restrict__ cnt,
    const unsigned short* __restrict__ idx, float* __restrict__ out, int N,
    int S, int NSEG, int L) {
  const int b = blockIdx.x;
  const int tid = threadIdx.x;
  const int lane = tid & 63;
  const int wid = tid >> 6;

  __shared__ int pfx[MAX_NSEG + 1];
  __shared__ int wtot[4];
  __shared__ int woff[4];

  int v = (tid < NSEG) ? cnt[b * NSEG + tid] : 0;
  int sv = v;
#pragma unroll
  for (int d = 1; d < 64; d <<= 1) {
    const int t = __shfl_up(sv, d, 64);
    if (lane >= d) sv += t;
  }
  if (lane == 63) wtot[wid] = sv;
  __syncthreads();
  if (tid == 0) {
    int a = 0;
#pragma unroll
    for (int w = 0; w < 4; ++w) {
      woff[w] = a;
      a += wtot[w];
    }
  }
  __syncthreads();
  const int incl = sv + woff[wid];
  if (tid < NSEG) pfx[tid + 1] = incl;
  if (tid == 0) pfx[0] = 0;
  __syncthreads();

  const int total = pfx[NSEG];
  if (tid < S) {
    float* o = out + ((size_t)b * S + tid) * F_DIM;
    if (tid < total) {
      int lo = 0, hi = NSEG - 1;
      while (lo < hi) {
        const int mid = (lo + hi + 1) >> 1;
        if (pfx[mid] <= tid) lo = mid;
        else hi = mid - 1;
      }
      const int s = lo;
      const int gi =
          s * L + (int)idx[((size_t)b * NSEG + s) * S + (tid - pfx[s])];
      const float* p = pts + (size_t)gi * F_DIM;
      o[0] = p[0];
      o[1] = p[1];
      o[2] = p[2];
      o[3] = p[3];
      o[4] = p[4];
    } else {
      o[0] = 0.0f;
      o[1] = 0.0f;
      o[2] = 0.0f;
      o[3] = 0.0f;
      o[4] = 0.0f;
    }
  }
}

// ---------------- Fallback: proven R1 single-kernel version ----------------
template <int BLOCK>
__global__ void __launch_bounds__(BLOCK) voxel_sampler_fallback(
    const float* __restrict__ pts, const float* __restrict__ boxes,
    float* __restrict__ out, int N, int S) {
  constexpr int NW = BLOCK / 64;
  const int b = blockIdx.x;
  const int tid = threadIdx.x;
  const int lane = tid & 63;
  const int wid = tid >> 6;

  const float cx = boxes[b * 7 + 0];
  const float cy = boxes[b * 7 + 1];
  const float hdx = __fmul_rn(boxes[b * 7 + 3], 0.5f);
  const float hdy = __fmul_rn(boxes[b * 7 + 4], 0.5f);
  const float r = __fmul_rn(
      __fsqrt_rn(__fadd_rn(__fmul_rn(hdx, hdx), __fmul_rn(hdy, hdy))),
      GAMMA_F);

  __shared__ int s_wsum[NW];
  __shared__ int s_count;
  if (tid == 0) s_count = 0;
  __syncthreads();

  float* outb = out + (size_t)b * S * F_DIM;

  for (int base = 0; base < N; base += BLOCK) {
    const int i = base + tid;
    bool sel = false;
    float x = 0.0f, y = 0.0f;
    if (i < N) {
      x = pts[i * F_DIM + 0];
      y = pts[i * F_DIM + 1];
      const float ddx = __fsub_rn(x, cx);
      const float ddy = __fsub_rn(y, cy);
      const float dis =
          __fsqrt_rn(__fadd_rn(__fmul_rn(ddx, ddx), __fmul_rn(ddy, ddy)));
      sel = (dis <= r);
    }
    const unsigned long long m = __ballot(sel);
    if (lane == 0) s_wsum[wid] = __popcll(m);
    __syncthreads();
    const int cbase = s_count;
    int wbase = 0;
    int tot = 0;
#pragma unroll
    for (int w = 0; w < NW; ++w) {
      const int v = s_wsum[w];
      if (w < wid) wbase += v;
      tot += v;
    }
    const int pos = cbase + wbase + __popcll(m & ((1ULL << lane) - 1ULL));
    if (sel && pos < S) {
      float* o = outb + pos * F_DIM;
      o[0] = x;
      o[1] = y;
      o[2] = pts[i * F_DIM + 2];
      o[3] = pts[i * F_DIM + 3];
      o[4] = pts[i * F_DIM + 4];
    }
    __syncthreads();
    if (tid == 0) s_count = cbase + tot;
    __syncthreads();
    if (cbase + tot >= S) break;
  }

  __syncthreads();
  int cnt = s_count;
  if (cnt > S) cnt = S;
  for (int j = cnt * F_DIM + tid; j < S * F_DIM; j += BLOCK) outb[j] = 0.0f;
}

extern "C" void kernel_launch(void* const* d_in, const int* in_sizes, int n_in,
                              void* d_out, int out_size, void* d_ws,
                              size_t ws_size, hipStream_t stream) {
  const float* pts = (const float*)d_in[0];
  const float* boxes = (const float*)d_in[1];
  float* out = (float*)d_out;

  const int N = in_sizes[0] / F_DIM;     // 200000
  const int B = in_sizes[1] / 7;         // 256
  const int S = out_size / (B * F_DIM);  // 128

  const int NSEG = 256;
  int L = ((N + NSEG - 1) / NSEG + 1) & ~1;  // even
  const int NGRP = B / BOXG;                 // 32
  constexpr int NWAVE = 16;                  // 1024-thread blocks

  const size_t sz_cnt = (size_t)B * NSEG * sizeof(int);
  const size_t off_idx = (sz_cnt + 255) & ~(size_t)255;
  const size_t sz_idx = (size_t)B * NSEG * S * sizeof(unsigned short);
  const size_t need = off_idx + sz_idx;

  const bool fast = (ws_size >= need) && (L >= 2) && (L <= MAXL) &&
                    (L - 1 <= 65535) && (B % BOXG == 0) && (S <= 256) &&
                    (NSEG <= MAX_NSEG) && (NGRP % NWAVE == 0) &&
                    ((size_t)L * NSEG >= (size_t)N);

  if (fast) {
    char* ws = (char*)d_ws;
    int* cnt = (int*)ws;
    unsigned short* idx = (unsigned short*)(ws + off_idx);

    const int bpg = NGRP / NWAVE;  // 2
    seg_lds_kernel<NWAVE><<<NSEG * bpg, NWAVE * 64, 0, stream>>>(
        pts, boxes, cnt, idx, N, S, NSEG, L, NGRP);
    gather_kernel<<<B, 256, 0, stream>>>(pts, cnt, idx, out, N, S, NSEG, L);
  } else {
    voxel_sampler_fallback<1024><<<B, 1024, 0, stream>>>(pts, boxes, out, N,
                                                         S);
  }
}